// Round 3
// baseline (782.661 us; speedup 1.0000x reference)
//
#include <hip/hip_runtime.h>

#define BN_EPS 1e-5f

static constexpr int D_IN = 128;

// ---------------- graph preprocessing ----------------
// NOTE: harness delivers integer inputs as int32 (NOT the reference's int64).

__global__ __launch_bounds__(256) void count_kernel(const int* __restrict__ dst, int E,
                                                    int* __restrict__ cnt) {
  int e = blockIdx.x * 256 + threadIdx.x;
  if (e < E) atomicAdd(&cnt[dst[e]], 1);
}

__global__ __launch_bounds__(256) void dinv_kernel(const int* __restrict__ cnt,
                                                   float* __restrict__ dinv, int n) {
  int i = blockIdx.x * 256 + threadIdx.x;
  if (i < n) dinv[i] = rsqrtf((float)cnt[i] + 1.0f);  // +1: self loop
}

// exclusive scan of cnt[0..n) -> rowptr, three-phase
__global__ __launch_bounds__(1024) void scan_sum_kernel(const int* __restrict__ cnt, int n,
                                                        int* __restrict__ bsum) {
  __shared__ int sdata[1024];
  int i = blockIdx.x * 1024 + threadIdx.x;
  sdata[threadIdx.x] = (i < n) ? cnt[i] : 0;
  __syncthreads();
  for (int s = 512; s > 0; s >>= 1) {
    if (threadIdx.x < s) sdata[threadIdx.x] += sdata[threadIdx.x + s];
    __syncthreads();
  }
  if (threadIdx.x == 0) bsum[blockIdx.x] = sdata[0];
}

__global__ void scan_off_kernel(const int* __restrict__ bsum, int nb,
                                int* __restrict__ boff, int* __restrict__ rowptr_last) {
  if (threadIdx.x == 0 && blockIdx.x == 0) {
    int run = 0;
    for (int b = 0; b < nb; ++b) { boff[b] = run; run += bsum[b]; }
    *rowptr_last = run;  // rowptr[N] = E
  }
}

__global__ __launch_bounds__(1024) void scan_final_kernel(const int* __restrict__ cnt, int n,
                                                          const int* __restrict__ boff,
                                                          int* __restrict__ rowptr) {
  __shared__ int wt[16];
  int i = blockIdx.x * 1024 + threadIdx.x;
  int lane = threadIdx.x & 63, w = threadIdx.x >> 6;
  int v = (i < n) ? cnt[i] : 0;
  int x = v;
  #pragma unroll
  for (int d = 1; d < 64; d <<= 1) {
    int t = __shfl_up(x, d, 64);
    if (lane >= d) x += t;
  }
  if (lane == 63) wt[w] = x;
  __syncthreads();
  if (threadIdx.x == 0) {
    int run = 0;
    #pragma unroll
    for (int k = 0; k < 16; ++k) { int t = wt[k]; wt[k] = run; run += t; }
  }
  __syncthreads();
  if (i < n) rowptr[i] = x - v + wt[w] + boff[blockIdx.x];
}

__global__ __launch_bounds__(256) void fill_kernel(const int* __restrict__ src,
                                                   const int* __restrict__ dst, int E,
                                                   const int* __restrict__ rowptr,
                                                   int* __restrict__ cursor, int* __restrict__ col) {
  int e = blockIdx.x * 256 + threadIdx.x;
  if (e < E) {
    int d = dst[e];
    int p = atomicAdd(&cursor[d], 1);
    col[rowptr[d] + p] = src[e];
  }
}

// ---------------- aggregation: out[i] = dinv[i]*(sum_j dinv[j]*in[j] + dinv[i]*in[i]) (+bias)(+x) -----

template<int V>
__device__ __forceinline__ void loadv(float* d, const float* p) {
  if constexpr (V == 4) *(float4*)d = *(const float4*)p;
  else                  *(float2*)d = *(const float2*)p;
}
template<int V>
__device__ __forceinline__ void storev(float* p, const float* d) {
  if constexpr (V == 4) *(float4*)p = *(const float4*)d;
  else                  *(float2*)p = *(const float2*)d;
}

template<int F, bool FINAL>
__global__ __launch_bounds__(256) void agg_kernel(const float* __restrict__ in,
                                                  const int* __restrict__ rowptr,
                                                  const int* __restrict__ col,
                                                  const float* __restrict__ dinv,
                                                  const float* __restrict__ bias,
                                                  const float* __restrict__ xres,
                                                  float* __restrict__ out, int n) {
  constexpr int V = F / 64;  // floats per lane
  int node = blockIdx.x * 4 + (threadIdx.x >> 6);
  if (node >= n) return;
  int lane = threadIdx.x & 63;
  const int off = lane * V;
  const size_t rowbase = (size_t)node * F + off;

  float di = dinv[node];
  float acc[V], v[V];
  loadv<V>(v, in + rowbase);           // self loop contribution
  #pragma unroll
  for (int j = 0; j < V; ++j) acc[j] = di * v[j];

  int start = __builtin_amdgcn_readfirstlane(rowptr[node]);
  int end   = __builtin_amdgcn_readfirstlane(rowptr[node + 1]);
  int e = start;
  for (; e + 2 <= end; e += 2) {
    int s0 = col[e], s1 = col[e + 1];
    float w0 = dinv[s0], w1 = dinv[s1];
    float v0[V], v1[V];
    loadv<V>(v0, in + (size_t)s0 * F + off);
    loadv<V>(v1, in + (size_t)s1 * F + off);
    #pragma unroll
    for (int j = 0; j < V; ++j) acc[j] = fmaf(w0, v0[j], acc[j]);
    #pragma unroll
    for (int j = 0; j < V; ++j) acc[j] = fmaf(w1, v1[j], acc[j]);
  }
  if (e < end) {
    int s0 = col[e];
    float w0 = dinv[s0];
    float v0[V];
    loadv<V>(v0, in + (size_t)s0 * F + off);
    #pragma unroll
    for (int j = 0; j < V; ++j) acc[j] = fmaf(w0, v0[j], acc[j]);
  }

  #pragma unroll
  for (int j = 0; j < V; ++j) acc[j] *= di;
  if (bias) {
    float b[V]; loadv<V>(b, bias + off);
    #pragma unroll
    for (int j = 0; j < V; ++j) acc[j] += b[j];
  }
  if constexpr (FINAL) {
    float xr[V]; loadv<V>(xr, xres + rowbase);
    #pragma unroll
    for (int j = 0; j < V; ++j) acc[j] += xr[j];
  }
  storev<V>(out + rowbase, acc);
}

// ---------------- fp32 GEMM: C[M,F] = A[M,K] @ W[K,F] (+bias) ----------------
// 64x64 tile, 256 threads, 4x4 micro-tile, K in chunks of 32

__global__ __launch_bounds__(256) void gemm_kernel(const float* __restrict__ A,
                                                   const float* __restrict__ W,
                                                   const float* __restrict__ bias,
                                                   float* __restrict__ C,
                                                   int M, int K, int F) {
  __shared__ float As[32][68];  // [k][m], padded: byte stride 272 ≡ 0 mod 16 (float4-aligned),
                                // cuts 8-way staging-write bank conflict to ≤4-way
  __shared__ float Ws[32][64];  // [k][n]
  const int tid = threadIdx.x;
  const int tx = tid & 15, ty = tid >> 4;
  const int bm = blockIdx.x * 64, bn = blockIdx.y * 64;
  float acc[4][4] = {};

  for (int k0 = 0; k0 < K; k0 += 32) {
    {  // stage A (transposed): 64 rows x 32 k
      int r = tid >> 3;
      int kq = (tid & 7) * 4;
      #pragma unroll
      for (int h = 0; h < 2; ++h) {
        int row = bm + r + h * 32;
        int rr = row < M ? row : M - 1;
        float4 a = *(const float4*)(A + (size_t)rr * K + k0 + kq);
        As[kq + 0][r + h * 32] = a.x;
        As[kq + 1][r + h * 32] = a.y;
        As[kq + 2][r + h * 32] = a.z;
        As[kq + 3][r + h * 32] = a.w;
      }
    }
    {  // stage W: 32 k x 64 n
      int r = tid >> 4;
      int c = (tid & 15) * 4;
      #pragma unroll
      for (int h = 0; h < 2; ++h)
        *(float4*)&Ws[r + h * 16][c] = *(const float4*)(W + (size_t)(k0 + r + h * 16) * F + bn + c);
    }
    __syncthreads();
    #pragma unroll
    for (int k = 0; k < 32; ++k) {
      float4 a = *(const float4*)&As[k][ty * 4];
      float4 b = *(const float4*)&Ws[k][tx * 4];
      float av[4] = {a.x, a.y, a.z, a.w};
      float bv[4] = {b.x, b.y, b.z, b.w};
      #pragma unroll
      for (int i = 0; i < 4; ++i)
        #pragma unroll
        for (int j = 0; j < 4; ++j)
          acc[i][j] = fmaf(av[i], bv[j], acc[i][j]);
    }
    __syncthreads();
  }

  float bv[4] = {0.f, 0.f, 0.f, 0.f};
  if (bias) {
    float4 bb = *(const float4*)(bias + bn + tx * 4);
    bv[0] = bb.x; bv[1] = bb.y; bv[2] = bb.z; bv[3] = bb.w;
  }
  #pragma unroll
  for (int i = 0; i < 4; ++i) {
    int row = bm + ty * 4 + i;
    if (row < M) {
      float4 o;
      o.x = acc[i][0] + bv[0];
      o.y = acc[i][1] + bv[1];
      o.z = acc[i][2] + bv[2];
      o.w = acc[i][3] + bv[3];
      *(float4*)(C + (size_t)row * F + bn + tx * 4) = o;
    }
  }
}

// ---------------- BatchNorm: deterministic per-block partials ----------------

template<int F>
__global__ __launch_bounds__(256) void stats_kernel(const float* __restrict__ m, int n,
                                                    float* __restrict__ partial) {
  constexpr int COLS = F / 4;       // float4 lanes across features
  constexpr int RG = 256 / COLS;    // row groups per block
  int c4 = threadIdx.x % COLS;
  int rg = threadIdx.x / COLS;
  float s[4] = {}, q[4] = {};
  for (int r = blockIdx.x * RG + rg; r < n; r += gridDim.x * RG) {
    float v[4];
    *(float4*)v = *(const float4*)(m + (size_t)r * F + c4 * 4);
    #pragma unroll
    for (int j = 0; j < 4; ++j) { s[j] += v[j]; q[j] = fmaf(v[j], v[j], q[j]); }
  }
  __shared__ float ls[256][8];
  #pragma unroll
  for (int j = 0; j < 4; ++j) { ls[threadIdx.x][j] = s[j]; ls[threadIdx.x][4 + j] = q[j]; }
  __syncthreads();
  if (rg == 0) {
    for (int g = 1; g < RG; ++g) {
      #pragma unroll
      for (int j = 0; j < 4; ++j) {
        s[j] += ls[g * COLS + c4][j];
        q[j] += ls[g * COLS + c4][4 + j];
      }
    }
    #pragma unroll
    for (int j = 0; j < 4; ++j) {
      partial[(size_t)blockIdx.x * 2 * F + c4 * 4 + j]     = s[j];
      partial[(size_t)blockIdx.x * 2 * F + F + c4 * 4 + j] = q[j];
    }
  }
}

template<int F>
__global__ void finalize_kernel(const float* __restrict__ partial, int nb, int n,
                                const float* __restrict__ g, const float* __restrict__ be,
                                float* __restrict__ scale, float* __restrict__ shift) {
  int c = threadIdx.x;
  if (c >= F) return;
  float s = 0.f, q = 0.f;
  for (int b = 0; b < nb; ++b) {
    s += partial[(size_t)b * 2 * F + c];
    q += partial[(size_t)b * 2 * F + F + c];
  }
  float inv_n = 1.0f / (float)n;
  float mu = s * inv_n;
  float var = q * inv_n - mu * mu;
  float rs = rsqrtf(var + BN_EPS);
  float sc = rs * g[c];
  scale[c] = sc;
  shift[c] = fmaf(-mu, sc, be[c]);
}

template<int F, bool RES>
__global__ __launch_bounds__(256) void apply_kernel(const float* __restrict__ m,
                                                    const float* __restrict__ scale,
                                                    const float* __restrict__ shift,
                                                    const float* __restrict__ res,
                                                    float* __restrict__ out, int n) {
  int i = blockIdx.x * 256 + threadIdx.x;  // float4 index
  if (i >= n * (F / 4)) return;
  int c = i & (F / 4 - 1);
  float4 v = ((const float4*)m)[i];
  float4 sc = ((const float4*)scale)[c];
  float4 sh = ((const float4*)shift)[c];
  float h0 = fmaxf(fmaf(v.x, sc.x, sh.x), 0.f);
  float h1 = fmaxf(fmaf(v.y, sc.y, sh.y), 0.f);
  float h2 = fmaxf(fmaf(v.z, sc.z, sh.z), 0.f);
  float h3 = fmaxf(fmaf(v.w, sc.w, sh.w), 0.f);
  if constexpr (RES) {
    float4 r = ((const float4*)res)[i];
    h0 += r.x; h1 += r.y; h2 += r.z; h3 += r.w;
  }
  float4 o; o.x = h0; o.y = h1; o.z = h2; o.w = h3;
  ((float4*)out)[i] = o;
}

// ---------------- launcher ----------------

extern "C" void kernel_launch(void* const* d_in, const int* in_sizes, int n_in,
                              void* d_out, int out_size, void* d_ws, size_t ws_size,
                              hipStream_t stream) {
  const float* x   = (const float*)d_in[0];
  const int*   ei  = (const int*)d_in[1];   // int32 per harness dtype rule
  const float* W0  = (const float*)d_in[2];
  const float* b0  = (const float*)d_in[3];
  const float* g0  = (const float*)d_in[4];
  const float* be0 = (const float*)d_in[5];
  const float* W1  = (const float*)d_in[6];
  const float* b1  = (const float*)d_in[7];
  const float* g1  = (const float*)d_in[8];
  const float* be1 = (const float*)d_in[9];
  const float* W2  = (const float*)d_in[10];
  const float* b2  = (const float*)d_in[11];
  float* out = (float*)d_out;

  const int N = in_sizes[0] / D_IN;
  const int E = in_sizes[1] / 2;
  const int* esrc = ei;
  const int* edst = ei + E;

  char* p = (char*)d_ws;
  auto alloc = [&](size_t bytes) { char* r = p; p += (bytes + 255) & ~(size_t)255; return r; };
  int* cnt     = (int*)alloc((size_t)N * 4);
  int* cursor  = (int*)alloc((size_t)N * 4);
  int* rowptr  = (int*)alloc(((size_t)N + 1) * 4);
  int* col     = (int*)alloc((size_t)E * 4);
  float* dinv  = (float*)alloc((size_t)N * 4);
  const int nb = (N + 1023) / 1024;
  int* bsum    = (int*)alloc((size_t)nb * 4);
  int* boff    = (int*)alloc((size_t)nb * 4);
  constexpr int SB = 128;
  float* partial = (float*)alloc((size_t)SB * 2 * 256 * 4);
  float* scalev  = (float*)alloc(256 * 4);
  float* shiftv  = (float*)alloc(256 * 4);
  float* B0 = (float*)alloc((size_t)N * 256 * 4);  // m0 / h0
  float* B1 = (float*)alloc((size_t)N * 256 * 4);  // m1; first half doubles as BA (disjoint live ranges)
  float* B2 = (float*)alloc((size_t)N * 256 * 4);  // a1 / h1
  float* BA = B1;  // [N,128] scratch: live in layers 0 & 2 only; B1 live in layer 1 only
  (void)ws_size; (void)n_in; (void)out_size;

  hipMemsetAsync(cnt, 0, (size_t)N * 4, stream);
  hipMemsetAsync(cursor, 0, (size_t)N * 4, stream);

  // graph preprocessing
  count_kernel<<<(E + 255) / 256, 256, 0, stream>>>(edst, E, cnt);
  dinv_kernel<<<(N + 255) / 256, 256, 0, stream>>>(cnt, dinv, N);
  scan_sum_kernel<<<nb, 1024, 0, stream>>>(cnt, N, bsum);
  scan_off_kernel<<<1, 64, 0, stream>>>(bsum, nb, boff, rowptr + N);
  scan_final_kernel<<<nb, 1024, 0, stream>>>(cnt, N, boff, rowptr);
  fill_kernel<<<(E + 255) / 256, 256, 0, stream>>>(esrc, edst, E, rowptr, cursor, col);

  const int aggGrid = (N + 3) / 4;

  // layer 0: aggregate-first (128 wide), then GEMM 128->256 (+b0), BN, ReLU
  agg_kernel<128, false><<<aggGrid, 256, 0, stream>>>(x, rowptr, col, dinv, nullptr, nullptr, BA, N);
  gemm_kernel<<<dim3((N + 63) / 64, 4), 256, 0, stream>>>(BA, W0, b0, B0, N, 128, 256);
  stats_kernel<256><<<SB, 256, 0, stream>>>(B0, N, partial);
  finalize_kernel<256><<<1, 256, 0, stream>>>(partial, SB, N, g0, be0, scalev, shiftv);
  apply_kernel<256, false><<<(N * 64 + 255) / 256, 256, 0, stream>>>(B0, scalev, shiftv, nullptr, B0, N);

  // layer 1: GEMM 256->256, aggregate (+b1), BN, ReLU, +h0
  gemm_kernel<<<dim3((N + 63) / 64, 4), 256, 0, stream>>>(B0, W1, nullptr, B1, N, 256, 256);
  agg_kernel<256, false><<<aggGrid, 256, 0, stream>>>(B1, rowptr, col, dinv, b1, nullptr, B2, N);
  stats_kernel<256><<<SB, 256, 0, stream>>>(B2, N, partial);
  finalize_kernel<256><<<1, 256, 0, stream>>>(partial, SB, N, g1, be1, scalev, shiftv);
  apply_kernel<256, true><<<(N * 64 + 255) / 256, 256, 0, stream>>>(B2, scalev, shiftv, B0, B2, N);

  // layer 2: GEMM 256->128, aggregate (+b2, +x) -> out
  gemm_kernel<<<dim3((N + 63) / 64, 2), 256, 0, stream>>>(B2, W2, nullptr, BA, N, 256, 128);
  agg_kernel<128, true><<<aggGrid, 256, 0, stream>>>(BA, rowptr, col, dinv, b2, x, out, N);
}

// Round 4
// 535.491 us; speedup vs baseline: 1.4616x; 1.4616x over previous
//
#include <hip/hip_runtime.h>

#define BN_EPS 1e-5f

static constexpr int D_IN = 128;

using u16 = unsigned short;
using f32x4  = __attribute__((ext_vector_type(4))) float;
using bf16x8 = __attribute__((ext_vector_type(8))) __bf16;

union FragU { uint4 u; bf16x8 v; };

__device__ __forceinline__ u16 f2bf(float f) {
  unsigned int u = __float_as_uint(f);
  u += 0x7FFFu + ((u >> 16) & 1u);   // RNE
  return (u16)(u >> 16);
}
__device__ __forceinline__ float bf2f(u16 h) {
  return __uint_as_float(((unsigned int)h) << 16);
}

// ---------------- graph preprocessing (int32 edge_index per harness rule) -----

__global__ __launch_bounds__(256) void count_kernel(const int* __restrict__ dst, int E,
                                                    int* __restrict__ cnt) {
  int e = blockIdx.x * 256 + threadIdx.x;
  if (e < E) atomicAdd(&cnt[dst[e]], 1);
}

__global__ __launch_bounds__(256) void dinv_kernel(const int* __restrict__ cnt,
                                                   float* __restrict__ dinv, int n) {
  int i = blockIdx.x * 256 + threadIdx.x;
  if (i < n) dinv[i] = rsqrtf((float)cnt[i] + 1.0f);  // +1: self loop
}

__global__ __launch_bounds__(1024) void scan_sum_kernel(const int* __restrict__ cnt, int n,
                                                        int* __restrict__ bsum) {
  __shared__ int sdata[1024];
  int i = blockIdx.x * 1024 + threadIdx.x;
  sdata[threadIdx.x] = (i < n) ? cnt[i] : 0;
  __syncthreads();
  for (int s = 512; s > 0; s >>= 1) {
    if (threadIdx.x < s) sdata[threadIdx.x] += sdata[threadIdx.x + s];
    __syncthreads();
  }
  if (threadIdx.x == 0) bsum[blockIdx.x] = sdata[0];
}

__global__ void scan_off_kernel(const int* __restrict__ bsum, int nb,
                                int* __restrict__ boff, int* __restrict__ rowptr_last) {
  if (threadIdx.x == 0 && blockIdx.x == 0) {
    int run = 0;
    for (int b = 0; b < nb; ++b) { boff[b] = run; run += bsum[b]; }
    *rowptr_last = run;
  }
}

__global__ __launch_bounds__(1024) void scan_final_kernel(const int* __restrict__ cnt, int n,
                                                          const int* __restrict__ boff,
                                                          int* __restrict__ rowptr) {
  __shared__ int wt[16];
  int i = blockIdx.x * 1024 + threadIdx.x;
  int lane = threadIdx.x & 63, w = threadIdx.x >> 6;
  int v = (i < n) ? cnt[i] : 0;
  int x = v;
  #pragma unroll
  for (int d = 1; d < 64; d <<= 1) {
    int t = __shfl_up(x, d, 64);
    if (lane >= d) x += t;
  }
  if (lane == 63) wt[w] = x;
  __syncthreads();
  if (threadIdx.x == 0) {
    int run = 0;
    #pragma unroll
    for (int k = 0; k < 16; ++k) { int t = wt[k]; wt[k] = run; run += t; }
  }
  __syncthreads();
  if (i < n) rowptr[i] = x - v + wt[w] + boff[blockIdx.x];
}

__global__ __launch_bounds__(256) void fill_kernel(const int* __restrict__ src,
                                                   const int* __restrict__ dst, int E,
                                                   const int* __restrict__ rowptr,
                                                   int* __restrict__ cursor, int* __restrict__ col) {
  int e = blockIdx.x * 256 + threadIdx.x;
  if (e < E) {
    int d = dst[e];
    int p = atomicAdd(&cursor[d], 1);
    col[rowptr[d] + p] = src[e];
  }
}

// ---------------- conversions ----------------

__global__ __launch_bounds__(256) void f2bf_kernel(const float* __restrict__ in,
                                                   u16* __restrict__ out, int n4) {
  int i = blockIdx.x * 256 + threadIdx.x;
  if (i < n4) {
    float4 v = ((const float4*)in)[i];
    u16 o[4] = { f2bf(v.x), f2bf(v.y), f2bf(v.z), f2bf(v.w) };
    ((uint2*)out)[i] = *(uint2*)o;
  }
}

// W [K][NN] fp32 -> Wt [NN][K] bf16
__global__ __launch_bounds__(256) void wtrans_kernel(const float* __restrict__ W,
                                                     u16* __restrict__ Wt, int K, int NN) {
  int idx = blockIdx.x * 256 + threadIdx.x;
  if (idx < K * NN) {
    int k = idx / NN, nc = idx - k * NN;
    Wt[(size_t)nc * K + k] = f2bf(W[idx]);
  }
}

// ---------------- aggregation over bf16 features ----------------
// out[i] = dinv[i]*(sum_j dinv[j]*in[j] + dinv[i]*in[i]) (+bias)(+x fp32 if FINAL)

template<int F, bool BIAS, bool FINAL>
__global__ __launch_bounds__(256) void agg_bf16(const u16* __restrict__ in,
                                                const int* __restrict__ rowptr,
                                                const int* __restrict__ col,
                                                const float* __restrict__ dinv,
                                                const float* __restrict__ bias,
                                                const float* __restrict__ xres,
                                                void* __restrict__ outv, int n) {
  constexpr int V = F / 64;  // bf16 elems per lane (2 or 4)
  int node = blockIdx.x * 4 + (threadIdx.x >> 6);
  if (node >= n) return;
  int lane = threadIdx.x & 63;
  const int off = lane * V;
  const size_t rowbase = (size_t)node * F + off;

  float di = dinv[node];
  float acc[V];
  {
    u16 t[V];
    if constexpr (V == 4) *(uint2*)t = *(const uint2*)(in + rowbase);
    else                  *(unsigned int*)t = *(const unsigned int*)(in + rowbase);
    #pragma unroll
    for (int j = 0; j < V; ++j) acc[j] = di * bf2f(t[j]);
  }

  int e   = __builtin_amdgcn_readfirstlane(rowptr[node]);
  int end = __builtin_amdgcn_readfirstlane(rowptr[node + 1]);
  for (; e + 2 <= end; e += 2) {
    int s0 = col[e], s1 = col[e + 1];
    float w0 = dinv[s0], w1 = dinv[s1];
    u16 t0[V], t1[V];
    if constexpr (V == 4) {
      *(uint2*)t0 = *(const uint2*)(in + (size_t)s0 * F + off);
      *(uint2*)t1 = *(const uint2*)(in + (size_t)s1 * F + off);
    } else {
      *(unsigned int*)t0 = *(const unsigned int*)(in + (size_t)s0 * F + off);
      *(unsigned int*)t1 = *(const unsigned int*)(in + (size_t)s1 * F + off);
    }
    #pragma unroll
    for (int j = 0; j < V; ++j) acc[j] = fmaf(w0, bf2f(t0[j]), acc[j]);
    #pragma unroll
    for (int j = 0; j < V; ++j) acc[j] = fmaf(w1, bf2f(t1[j]), acc[j]);
  }
  if (e < end) {
    int s0 = col[e];
    float w0 = dinv[s0];
    u16 t0[V];
    if constexpr (V == 4) *(uint2*)t0 = *(const uint2*)(in + (size_t)s0 * F + off);
    else                  *(unsigned int*)t0 = *(const unsigned int*)(in + (size_t)s0 * F + off);
    #pragma unroll
    for (int j = 0; j < V; ++j) acc[j] = fmaf(w0, bf2f(t0[j]), acc[j]);
  }

  #pragma unroll
  for (int j = 0; j < V; ++j) acc[j] *= di;
  if constexpr (BIAS) {
    #pragma unroll
    for (int j = 0; j < V; ++j) acc[j] += bias[off + j];
  }
  if constexpr (FINAL) {
    float* out = (float*)outv;
    float xr[V];
    if constexpr (V == 2) *(float2*)xr = *(const float2*)(xres + rowbase);
    else                  *(float4*)xr = *(const float4*)(xres + rowbase);
    #pragma unroll
    for (int j = 0; j < V; ++j) acc[j] += xr[j];
    if constexpr (V == 2) *(float2*)(out + rowbase) = *(float2*)acc;
    else                  *(float4*)(out + rowbase) = *(float4*)acc;
  } else {
    u16* out = (u16*)outv;
    u16 o[V];
    #pragma unroll
    for (int j = 0; j < V; ++j) o[j] = f2bf(acc[j]);
    if constexpr (V == 4) *(uint2*)(out + rowbase) = *(uint2*)o;
    else                  *(unsigned int*)(out + rowbase) = *(unsigned int*)o;
  }
}

// ---------------- bf16 MFMA GEMM: C[M,NN] = A[M,K] @ Wt[NN,K]^T (+bias) -------
// 128x128 tile, 256 threads (4 waves 2x2), BK=64, mfma_f32_16x16x32_bf16.
// LDS XOR-swizzle: 16B chunk index c stored at c^(row&7) (involution), so
// frag ds_read_b128 (lanes 0-15 = 16 consecutive rows, same c) spreads across
// 8 chunk slots -> <=2-way bank aliasing (free). Same k->(lanegroup,elem)
// rule for A and B makes the MFMA dot product k-permutation invariant.

template<int K, int NN, bool BIAS>
__global__ __launch_bounds__(256) void gemm_bf16(const u16* __restrict__ A,
                                                 const u16* __restrict__ Wt,
                                                 const float* __restrict__ bias,
                                                 u16* __restrict__ C, int M) {
  __shared__ u16 As[128 * 64];
  __shared__ u16 Bs[128 * 64];
  const int tid = threadIdx.x;
  const int lane = tid & 63;
  const int wid = tid >> 6;
  const int wm = wid >> 1, wn = wid & 1;
  const int bm = blockIdx.x * 128;
  const int bn = blockIdx.y * 128;

  f32x4 acc[4][4] = {};

  const int srow = tid >> 3;    // 0..31
  const int schunk = tid & 7;   // 16B chunk within 128B row

  for (int k0 = 0; k0 < K; k0 += 64) {
    #pragma unroll
    for (int p = 0; p < 4; ++p) {  // A: 128 rows x 64 k
      int r = srow + p * 32;
      int rg = bm + r; if (rg >= M) rg = M - 1;
      uint4 d = *(const uint4*)(A + (size_t)rg * K + k0 + schunk * 8);
      *(uint4*)(As + r * 64 + ((schunk ^ (r & 7)) * 8)) = d;
    }
    #pragma unroll
    for (int p = 0; p < 4; ++p) {  // B: 128 cols x 64 k
      int r = srow + p * 32;
      uint4 d = *(const uint4*)(Wt + (size_t)(bn + r) * K + k0 + schunk * 8);
      *(uint4*)(Bs + r * 64 + ((schunk ^ (r & 7)) * 8)) = d;
    }
    __syncthreads();

    #pragma unroll
    for (int ks = 0; ks < 2; ++ks) {
      FragU a[4], b[4];
      #pragma unroll
      for (int mt = 0; mt < 4; ++mt) {
        int r = wm * 64 + mt * 16 + (lane & 15);
        int c = ks * 4 + (lane >> 4);
        a[mt].u = *(const uint4*)(As + r * 64 + ((c ^ (r & 7)) * 8));
      }
      #pragma unroll
      for (int nt = 0; nt < 4; ++nt) {
        int r = wn * 64 + nt * 16 + (lane & 15);
        int c = ks * 4 + (lane >> 4);
        b[nt].u = *(const uint4*)(Bs + r * 64 + ((c ^ (r & 7)) * 8));
      }
      #pragma unroll
      for (int mt = 0; mt < 4; ++mt)
        #pragma unroll
        for (int nt = 0; nt < 4; ++nt)
          acc[mt][nt] = __builtin_amdgcn_mfma_f32_16x16x32_bf16(a[mt].v, b[nt].v,
                                                                acc[mt][nt], 0, 0, 0);
    }
    __syncthreads();
  }

  // epilogue: C/D frag mapping col=lane&15, row=(lane>>4)*4+j (m89-verified)
  #pragma unroll
  for (int nt = 0; nt < 4; ++nt) {
    int gc = bn + wn * 64 + nt * 16 + (lane & 15);
    float bv = 0.f;
    if constexpr (BIAS) bv = bias[gc];
    #pragma unroll
    for (int mt = 0; mt < 4; ++mt) {
      int gr0 = bm + wm * 64 + mt * 16 + (lane >> 4) * 4;
      #pragma unroll
      for (int j = 0; j < 4; ++j) {
        int gr = gr0 + j;
        if (gr < M) C[(size_t)gr * NN + gc] = f2bf(acc[mt][nt][j] + bv);
      }
    }
  }
}

// ---------------- BatchNorm over bf16 activations ----------------

template<int F>
__global__ __launch_bounds__(256) void stats_bf16(const u16* __restrict__ m, int n,
                                                  float* __restrict__ partial) {
  constexpr int COLS = F / 4;
  constexpr int RG = 256 / COLS;
  int c4 = threadIdx.x % COLS;
  int rg = threadIdx.x / COLS;
  float s[4] = {}, q[4] = {};
  for (int r = blockIdx.x * RG + rg; r < n; r += gridDim.x * RG) {
    u16 t[4];
    *(uint2*)t = *(const uint2*)(m + (size_t)r * F + c4 * 4);
    #pragma unroll
    for (int j = 0; j < 4; ++j) { float v = bf2f(t[j]); s[j] += v; q[j] = fmaf(v, v, q[j]); }
  }
  __shared__ float ls[256][8];
  #pragma unroll
  for (int j = 0; j < 4; ++j) { ls[threadIdx.x][j] = s[j]; ls[threadIdx.x][4 + j] = q[j]; }
  __syncthreads();
  if (rg == 0) {
    for (int g = 1; g < RG; ++g) {
      #pragma unroll
      for (int j = 0; j < 4; ++j) {
        s[j] += ls[g * COLS + c4][j];
        q[j] += ls[g * COLS + c4][4 + j];
      }
    }
    #pragma unroll
    for (int j = 0; j < 4; ++j) {
      partial[(size_t)blockIdx.x * 2 * F + c4 * 4 + j]     = s[j];
      partial[(size_t)blockIdx.x * 2 * F + F + c4 * 4 + j] = q[j];
    }
  }
}

template<int F>
__global__ void finalize_kernel(const float* __restrict__ partial, int nb, int n,
                                const float* __restrict__ g, const float* __restrict__ be,
                                float* __restrict__ scale, float* __restrict__ shift) {
  int c = threadIdx.x;
  if (c >= F) return;
  float s = 0.f, q = 0.f;
  for (int b = 0; b < nb; ++b) {
    s += partial[(size_t)b * 2 * F + c];
    q += partial[(size_t)b * 2 * F + F + c];
  }
  float inv_n = 1.0f / (float)n;
  float mu = s * inv_n;
  float var = q * inv_n - mu * mu;
  float rs = rsqrtf(var + BN_EPS);
  float sc = rs * g[c];
  scale[c] = sc;
  shift[c] = fmaf(-mu, sc, be[c]);
}

template<int F, bool RES>
__global__ __launch_bounds__(256) void apply_bf16(const u16* __restrict__ m,
                                                  const float* __restrict__ scale,
                                                  const float* __restrict__ shift,
                                                  const u16* __restrict__ res,
                                                  u16* __restrict__ out, int n) {
  int i = blockIdx.x * 256 + threadIdx.x;  // group of 4 feats
  if (i >= n * (F / 4)) return;
  int c = i & (F / 4 - 1);
  u16 t[4];
  *(uint2*)t = *(const uint2*)(m + (size_t)i * 4);
  float4 sc = ((const float4*)scale)[c];
  float4 sh = ((const float4*)shift)[c];
  float h[4];
  h[0] = fmaxf(fmaf(bf2f(t[0]), sc.x, sh.x), 0.f);
  h[1] = fmaxf(fmaf(bf2f(t[1]), sc.y, sh.y), 0.f);
  h[2] = fmaxf(fmaf(bf2f(t[2]), sc.z, sh.z), 0.f);
  h[3] = fmaxf(fmaf(bf2f(t[3]), sc.w, sh.w), 0.f);
  if constexpr (RES) {
    u16 r[4];
    *(uint2*)r = *(const uint2*)(res + (size_t)i * 4);
    #pragma unroll
    for (int j = 0; j < 4; ++j) h[j] += bf2f(r[j]);
  }
  u16 o[4] = { f2bf(h[0]), f2bf(h[1]), f2bf(h[2]), f2bf(h[3]) };
  *(uint2*)(out + (size_t)i * 4) = *(uint2*)o;
}

// ---------------- launcher ----------------

extern "C" void kernel_launch(void* const* d_in, const int* in_sizes, int n_in,
                              void* d_out, int out_size, void* d_ws, size_t ws_size,
                              hipStream_t stream) {
  const float* x   = (const float*)d_in[0];
  const int*   ei  = (const int*)d_in[1];   // int32 per harness dtype rule
  const float* W0  = (const float*)d_in[2];
  const float* b0  = (const float*)d_in[3];
  const float* g0  = (const float*)d_in[4];
  const float* be0 = (const float*)d_in[5];
  const float* W1  = (const float*)d_in[6];
  const float* b1  = (const float*)d_in[7];
  const float* g1  = (const float*)d_in[8];
  const float* be1 = (const float*)d_in[9];
  const float* W2  = (const float*)d_in[10];
  const float* b2  = (const float*)d_in[11];
  float* out = (float*)d_out;

  const int N = in_sizes[0] / D_IN;
  const int E = in_sizes[1] / 2;
  const int* esrc = ei;
  const int* edst = ei + E;

  char* p = (char*)d_ws;
  auto alloc = [&](size_t bytes) { char* r = p; p += (bytes + 255) & ~(size_t)255; return r; };
  int* cnt     = (int*)alloc((size_t)N * 4);
  int* cursor  = (int*)alloc((size_t)N * 4);
  int* rowptr  = (int*)alloc(((size_t)N + 1) * 4);
  int* col     = (int*)alloc((size_t)E * 4);
  float* dinv  = (float*)alloc((size_t)N * 4);
  const int nb = (N + 1023) / 1024;
  int* bsum    = (int*)alloc((size_t)nb * 4);
  int* boff    = (int*)alloc((size_t)nb * 4);
  constexpr int SB = 128;
  float* partial = (float*)alloc((size_t)SB * 2 * 256 * 4);
  float* scalev  = (float*)alloc(256 * 4);
  float* shiftv  = (float*)alloc(256 * 4);
  u16* Wt0 = (u16*)alloc((size_t)256 * 128 * 2);
  u16* Wt1 = (u16*)alloc((size_t)256 * 256 * 2);
  u16* Wt2 = (u16*)alloc((size_t)128 * 256 * 2);
  // activation slots (aliased by disjoint live ranges):
  u16* slotX  = (u16*)alloc((size_t)N * 128 * 2);  // x_bf (L0), then m2 (L2)
  u16* slotAM = (u16*)alloc((size_t)N * 256 * 2);  // a0 (first half, L0), then m1 (L1)
  u16* slotMH = (u16*)alloc((size_t)N * 256 * 2);  // m0 -> h0 in-place
  u16* slotAH = (u16*)alloc((size_t)N * 256 * 2);  // a1 -> h1 in-place
  u16* x_bf = slotX;  u16* m2 = slotX;
  u16* a0   = slotAM; u16* m1 = slotAM;
  u16* m0   = slotMH; u16* h0 = slotMH;
  u16* a1   = slotAH; u16* h1 = slotAH;
  (void)ws_size; (void)n_in; (void)out_size;

  hipMemsetAsync(cnt, 0, (size_t)N * 4, stream);
  hipMemsetAsync(cursor, 0, (size_t)N * 4, stream);

  // weight transpose+convert, x convert
  wtrans_kernel<<<(128 * 256 + 255) / 256, 256, 0, stream>>>(W0, Wt0, 128, 256);
  wtrans_kernel<<<(256 * 256 + 255) / 256, 256, 0, stream>>>(W1, Wt1, 256, 256);
  wtrans_kernel<<<(256 * 128 + 255) / 256, 256, 0, stream>>>(W2, Wt2, 256, 128);
  f2bf_kernel<<<(N * 32 + 255) / 256, 256, 0, stream>>>(x, x_bf, N * 32);

  // graph preprocessing
  count_kernel<<<(E + 255) / 256, 256, 0, stream>>>(edst, E, cnt);
  dinv_kernel<<<(N + 255) / 256, 256, 0, stream>>>(cnt, dinv, N);
  scan_sum_kernel<<<nb, 1024, 0, stream>>>(cnt, N, bsum);
  scan_off_kernel<<<1, 64, 0, stream>>>(bsum, nb, boff, rowptr + N);
  scan_final_kernel<<<nb, 1024, 0, stream>>>(cnt, N, boff, rowptr);
  fill_kernel<<<(E + 255) / 256, 256, 0, stream>>>(esrc, edst, E, rowptr, cursor, col);

  const int aggGrid = (N + 3) / 4;
  const int MB = (N + 127) / 128;

  // layer 0: a0 = Agg(x); m0 = a0@W0 + b0; h0 = relu(bn(m0))
  agg_bf16<128, false, false><<<aggGrid, 256, 0, stream>>>(x_bf, rowptr, col, dinv,
                                                           nullptr, nullptr, a0, N);
  gemm_bf16<128, 256, true><<<dim3(MB, 2), 256, 0, stream>>>(a0, Wt0, b0, m0, N);
  stats_bf16<256><<<SB, 256, 0, stream>>>(m0, N, partial);
  finalize_kernel<256><<<1, 256, 0, stream>>>(partial, SB, N, g0, be0, scalev, shiftv);
  apply_bf16<256, false><<<(N * 64 + 255) / 256, 256, 0, stream>>>(m0, scalev, shiftv,
                                                                   nullptr, h0, N);

  // layer 1: m1 = h0@W1; a1 = Agg(m1)+b1; h1 = relu(bn(a1)) + h0
  gemm_bf16<256, 256, false><<<dim3(MB, 2), 256, 0, stream>>>(h0, Wt1, nullptr, m1, N);
  agg_bf16<256, true, false><<<aggGrid, 256, 0, stream>>>(m1, rowptr, col, dinv,
                                                          b1, nullptr, a1, N);
  stats_bf16<256><<<SB, 256, 0, stream>>>(a1, N, partial);
  finalize_kernel<256><<<1, 256, 0, stream>>>(partial, SB, N, g1, be1, scalev, shiftv);
  apply_bf16<256, true><<<(N * 64 + 255) / 256, 256, 0, stream>>>(a1, scalev, shiftv,
                                                                  h0, h1, N);

  // layer 2: m2 = h1@W2; out = Agg(m2) + b2 + x (x fp32 exact)
  gemm_bf16<256, 128, false><<<dim3(MB, 1), 256, 0, stream>>>(h1, Wt2, nullptr, m2, N);
  agg_bf16<128, true, true><<<aggGrid, 256, 0, stream>>>(m2, rowptr, col, dinv,
                                                         b2, x, out, N);
}

// Round 5
// 439.467 us; speedup vs baseline: 1.7809x; 1.2185x over previous
//
#include <hip/hip_runtime.h>

#define BN_EPS 1e-5f

static constexpr int D_IN = 128;

using u16 = unsigned short;
using f32x4  = __attribute__((ext_vector_type(4))) float;
using bf16x8 = __attribute__((ext_vector_type(8))) __bf16;

union FragU { uint4 u; bf16x8 v; };

__device__ __forceinline__ u16 f2bf(float f) {
  unsigned int u = __float_as_uint(f);
  u += 0x7FFFu + ((u >> 16) & 1u);   // RNE
  return (u16)(u >> 16);
}
__device__ __forceinline__ float bf2f(u16 h) {
  return __uint_as_float(((unsigned int)h) << 16);
}

// ---------------- graph preprocessing (int32 edge_index per harness rule) -----

__global__ __launch_bounds__(256) void zero_kernel(int* __restrict__ p, int n) {
  int i = blockIdx.x * 256 + threadIdx.x;
  if (i < n) p[i] = 0;
}

__global__ __launch_bounds__(256) void count_kernel(const int* __restrict__ dst, int E,
                                                    int* __restrict__ cnt) {
  int e = blockIdx.x * 256 + threadIdx.x;
  if (e < E) atomicAdd(&cnt[dst[e]], 1);
}

// block sums for scan + dinv = rsqrt(deg+1) fused (same cnt read)
__global__ __launch_bounds__(1024) void scan_sum_kernel(const int* __restrict__ cnt, int n,
                                                        int* __restrict__ bsum,
                                                        float* __restrict__ dinv) {
  __shared__ int sdata[1024];
  int i = blockIdx.x * 1024 + threadIdx.x;
  int v = (i < n) ? cnt[i] : 0;
  if (i < n) dinv[i] = rsqrtf((float)v + 1.0f);  // +1: self loop
  sdata[threadIdx.x] = v;
  __syncthreads();
  for (int s = 512; s > 0; s >>= 1) {
    if (threadIdx.x < s) sdata[threadIdx.x] += sdata[threadIdx.x + s];
    __syncthreads();
  }
  if (threadIdx.x == 0) bsum[blockIdx.x] = sdata[0];
}

__global__ void scan_off_kernel(const int* __restrict__ bsum, int nb,
                                int* __restrict__ boff, int* __restrict__ rowptr_last) {
  if (threadIdx.x == 0 && blockIdx.x == 0) {
    int run = 0;
    for (int b = 0; b < nb; ++b) { boff[b] = run; run += bsum[b]; }
    *rowptr_last = run;
  }
}

__global__ __launch_bounds__(1024) void scan_final_kernel(const int* __restrict__ cnt, int n,
                                                          const int* __restrict__ boff,
                                                          int* __restrict__ rowptr) {
  __shared__ int wt[16];
  int i = blockIdx.x * 1024 + threadIdx.x;
  int lane = threadIdx.x & 63, w = threadIdx.x >> 6;
  int v = (i < n) ? cnt[i] : 0;
  int x = v;
  #pragma unroll
  for (int d = 1; d < 64; d <<= 1) {
    int t = __shfl_up(x, d, 64);
    if (lane >= d) x += t;
  }
  if (lane == 63) wt[w] = x;
  __syncthreads();
  if (threadIdx.x == 0) {
    int run = 0;
    #pragma unroll
    for (int k = 0; k < 16; ++k) { int t = wt[k]; wt[k] = run; run += t; }
  }
  __syncthreads();
  if (i < n) rowptr[i] = x - v + wt[w] + boff[blockIdx.x];
}

__global__ __launch_bounds__(256) void fill_kernel(const int* __restrict__ src,
                                                   const int* __restrict__ dst, int E,
                                                   const int* __restrict__ rowptr,
                                                   int* __restrict__ cursor, int* __restrict__ col) {
  int e = blockIdx.x * 256 + threadIdx.x;
  if (e < E) {
    int d = dst[e];
    int p = atomicAdd(&cursor[d], 1);
    col[rowptr[d] + p] = src[e];
  }
}

// ---------------- fused conversions: x->bf16, W0/W1/W2 -> transposed bf16 -----

__global__ __launch_bounds__(256) void prep_kernel(const float* __restrict__ x, u16* __restrict__ x_bf,
                                                   const float* __restrict__ W0, u16* __restrict__ Wt0,
                                                   const float* __restrict__ W1, u16* __restrict__ Wt1,
                                                   const float* __restrict__ W2, u16* __restrict__ Wt2,
                                                   int N, int BX) {
  int b = blockIdx.x, tid = threadIdx.x;
  if (b < BX) {
    int i = b * 256 + tid;
    if (i < N * 32) {
      float4 v = ((const float4*)x)[i];
      u16 o[4] = { f2bf(v.x), f2bf(v.y), f2bf(v.z), f2bf(v.w) };
      ((uint2*)x_bf)[i] = *(uint2*)o;
    }
  } else if (b < BX + 128) {            // W0 [128][256] -> Wt0 [256][128]
    int idx = (b - BX) * 256 + tid;
    int k = idx >> 8, nc = idx & 255;
    Wt0[nc * 128 + k] = f2bf(W0[idx]);
  } else if (b < BX + 384) {            // W1 [256][256] -> Wt1 [256][256]
    int idx = (b - BX - 128) * 256 + tid;
    int k = idx >> 8, nc = idx & 255;
    Wt1[nc * 256 + k] = f2bf(W1[idx]);
  } else {                              // W2 [256][128] -> Wt2 [128][256]
    int idx = (b - BX - 384) * 256 + tid;
    int k = idx >> 7, nc = idx & 127;
    Wt2[nc * 256 + k] = f2bf(W2[idx]);
  }
}

// ---------------- aggregation over bf16 features ----------------
// out[i] = dinv[i]*(sum_j dinv[j]*in[j] + dinv[i]*in[i]) (+bias)(+x fp32 if FINAL)

template<int F, bool BIAS, bool FINAL>
__global__ __launch_bounds__(256) void agg_bf16(const u16* __restrict__ in,
                                                const int* __restrict__ rowptr,
                                                const int* __restrict__ col,
                                                const float* __restrict__ dinv,
                                                const float* __restrict__ bias,
                                                const float* __restrict__ xres,
                                                void* __restrict__ outv, int n) {
  constexpr int V = F / 64;  // bf16 elems per lane (2 or 4)
  int node = blockIdx.x * 4 + (threadIdx.x >> 6);
  if (node >= n) return;
  int lane = threadIdx.x & 63;
  const int off = lane * V;
  const size_t rowbase = (size_t)node * F + off;

  float di = dinv[node];
  float acc[V];
  {
    u16 t[V];
    if constexpr (V == 4) *(uint2*)t = *(const uint2*)(in + rowbase);
    else                  *(unsigned int*)t = *(const unsigned int*)(in + rowbase);
    #pragma unroll
    for (int j = 0; j < V; ++j) acc[j] = di * bf2f(t[j]);
  }

  int e   = __builtin_amdgcn_readfirstlane(rowptr[node]);
  int end = __builtin_amdgcn_readfirstlane(rowptr[node + 1]);
  for (; e + 4 <= end; e += 4) {       // 4 gather rows in flight
    int s0 = col[e], s1 = col[e + 1], s2 = col[e + 2], s3 = col[e + 3];
    float w0 = dinv[s0], w1 = dinv[s1], w2 = dinv[s2], w3 = dinv[s3];
    u16 t0[V], t1[V], t2[V], t3[V];
    if constexpr (V == 4) {
      *(uint2*)t0 = *(const uint2*)(in + (size_t)s0 * F + off);
      *(uint2*)t1 = *(const uint2*)(in + (size_t)s1 * F + off);
      *(uint2*)t2 = *(const uint2*)(in + (size_t)s2 * F + off);
      *(uint2*)t3 = *(const uint2*)(in + (size_t)s3 * F + off);
    } else {
      *(unsigned int*)t0 = *(const unsigned int*)(in + (size_t)s0 * F + off);
      *(unsigned int*)t1 = *(const unsigned int*)(in + (size_t)s1 * F + off);
      *(unsigned int*)t2 = *(const unsigned int*)(in + (size_t)s2 * F + off);
      *(unsigned int*)t3 = *(const unsigned int*)(in + (size_t)s3 * F + off);
    }
    #pragma unroll
    for (int j = 0; j < V; ++j) acc[j] = fmaf(w0, bf2f(t0[j]), acc[j]);
    #pragma unroll
    for (int j = 0; j < V; ++j) acc[j] = fmaf(w1, bf2f(t1[j]), acc[j]);
    #pragma unroll
    for (int j = 0; j < V; ++j) acc[j] = fmaf(w2, bf2f(t2[j]), acc[j]);
    #pragma unroll
    for (int j = 0; j < V; ++j) acc[j] = fmaf(w3, bf2f(t3[j]), acc[j]);
  }
  for (; e < end; ++e) {
    int s0 = col[e];
    float w0 = dinv[s0];
    u16 t0[V];
    if constexpr (V == 4) *(uint2*)t0 = *(const uint2*)(in + (size_t)s0 * F + off);
    else                  *(unsigned int*)t0 = *(const unsigned int*)(in + (size_t)s0 * F + off);
    #pragma unroll
    for (int j = 0; j < V; ++j) acc[j] = fmaf(w0, bf2f(t0[j]), acc[j]);
  }

  #pragma unroll
  for (int j = 0; j < V; ++j) acc[j] *= di;
  if constexpr (BIAS) {
    #pragma unroll
    for (int j = 0; j < V; ++j) acc[j] += bias[off + j];
  }
  if constexpr (FINAL) {
    float* out = (float*)outv;
    float xr[V];
    if constexpr (V == 2) *(float2*)xr = *(const float2*)(xres + rowbase);
    else                  *(float4*)xr = *(const float4*)(xres + rowbase);
    #pragma unroll
    for (int j = 0; j < V; ++j) acc[j] += xr[j];
    if constexpr (V == 2) *(float2*)(out + rowbase) = *(float2*)acc;
    else                  *(float4*)(out + rowbase) = *(float4*)acc;
  } else {
    u16* out = (u16*)outv;
    u16 o[V];
    #pragma unroll
    for (int j = 0; j < V; ++j) o[j] = f2bf(acc[j]);
    if constexpr (V == 4) *(uint2*)(out + rowbase) = *(uint2*)o;
    else                  *(unsigned int*)(out + rowbase) = *(unsigned int*)o;
  }
}

// ---------------- bf16 MFMA GEMM: C[M,NN] = A[M,K] @ Wt[NN,K]^T (+bias) -------
// 128x128 tile, 256 threads (4 waves 2x2), BK=64, mfma_f32_16x16x32_bf16.
// global_load_lds width-16 staging with the XOR swizzle applied to the GLOBAL
// source chunk (linear LDS dest = tid*16 per wave); reader un-swizzles with the
// same involution c^(r&7). Double-buffered: STAGE(t+1) issued before compute(t)
// so next-tile HBM latency hides under ds_read+MFMA; __syncthreads drains.
// STATS: per-block BN partial sums (padded rows masked) via shfl + LDS atomics.

template<int K, int NN, bool BIAS, bool STATS>
__global__ __launch_bounds__(256) void gemm_bf16(const u16* __restrict__ A,
                                                 const u16* __restrict__ Wt,
                                                 const float* __restrict__ bias,
                                                 u16* __restrict__ C,
                                                 float* __restrict__ partial, int M) {
  __shared__ u16 As[2][128 * 64];
  __shared__ u16 Bs[2][128 * 64];
  __shared__ float sstat[256];
  const int tid = threadIdx.x;
  const int lane = tid & 63;
  const int wid = tid >> 6;
  const int wm = wid >> 1, wn = wid & 1;
  const int bm = blockIdx.x * 128;
  const int bn = blockIdx.y * 128;
  const int srow = tid >> 3;    // 0..31
  const int schunk = tid & 7;   // 16B chunk slot within 128B row

  if constexpr (STATS) sstat[tid] = 0.f;

  f32x4 acc[4][4] = {};

  auto stage = [&](int buf, int k0) {
    #pragma unroll
    for (int p = 0; p < 4; ++p) {  // A: 128 rows x 64 k
      int r = srow + p * 32;
      int rg = bm + r; if (rg >= M) rg = M - 1;
      int sc = schunk ^ (r & 7);   // pre-swizzled global source chunk
      __builtin_amdgcn_global_load_lds(
          (const __attribute__((address_space(1))) void*)(A + (size_t)rg * K + k0 + sc * 8),
          (__attribute__((address_space(3))) void*)(&As[buf][r * 64 + schunk * 8]),
          16, 0, 0);
    }
    #pragma unroll
    for (int p = 0; p < 4; ++p) {  // B: 128 cols x 64 k
      int r = srow + p * 32;
      int sc = schunk ^ (r & 7);
      __builtin_amdgcn_global_load_lds(
          (const __attribute__((address_space(1))) void*)(Wt + (size_t)(bn + r) * K + k0 + sc * 8),
          (__attribute__((address_space(3))) void*)(&Bs[buf][r * 64 + schunk * 8]),
          16, 0, 0);
    }
  };

  stage(0, 0);
  __syncthreads();

  constexpr int NT = K / 64;
  int buf = 0;
  #pragma unroll
  for (int t = 0; t < NT; ++t) {
    if (t + 1 < NT) stage(buf ^ 1, (t + 1) * 64);   // prefetch next tile
    #pragma unroll
    for (int ks = 0; ks < 2; ++ks) {
      FragU a[4], b[4];
      #pragma unroll
      for (int mt = 0; mt < 4; ++mt) {
        int r = wm * 64 + mt * 16 + (lane & 15);
        int c = ks * 4 + (lane >> 4);
        a[mt].u = *(const uint4*)(&As[buf][r * 64 + ((c ^ (r & 7)) * 8)]);
      }
      #pragma unroll
      for (int nt = 0; nt < 4; ++nt) {
        int r = wn * 64 + nt * 16 + (lane & 15);
        int c = ks * 4 + (lane >> 4);
        b[nt].u = *(const uint4*)(&Bs[buf][r * 64 + ((c ^ (r & 7)) * 8)]);
      }
      #pragma unroll
      for (int mt = 0; mt < 4; ++mt)
        #pragma unroll
        for (int nt = 0; nt < 4; ++nt)
          acc[mt][nt] = __builtin_amdgcn_mfma_f32_16x16x32_bf16(a[mt].v, b[nt].v,
                                                                acc[mt][nt], 0, 0, 0);
    }
    __syncthreads();   // staged buf^1 complete + all waves done reading buf
    buf ^= 1;
  }

  // epilogue: C/D frag mapping col=lane&15, row=(lane>>4)*4+j (m89-verified)
  #pragma unroll
  for (int nt = 0; nt < 4; ++nt) {
    int cl = wn * 64 + nt * 16 + (lane & 15);
    int gc = bn + cl;
    float bv = 0.f;
    if constexpr (BIAS) bv = bias[gc];
    float cs = 0.f, cq = 0.f;
    #pragma unroll
    for (int mt = 0; mt < 4; ++mt) {
      int gr0 = bm + wm * 64 + mt * 16 + (lane >> 4) * 4;
      #pragma unroll
      for (int j = 0; j < 4; ++j) {
        int gr = gr0 + j;
        if (gr < M) {
          float v = acc[mt][nt][j] + bv;
          C[(size_t)gr * NN + gc] = f2bf(v);
          if constexpr (STATS) { cs += v; cq = fmaf(v, v, cq); }
        }
      }
    }
    if constexpr (STATS) {
      cs += __shfl_xor(cs, 16, 64); cq += __shfl_xor(cq, 16, 64);
      cs += __shfl_xor(cs, 32, 64); cq += __shfl_xor(cq, 32, 64);
      if ((lane >> 4) == 0) {   // lanes 0-15 hold full 64-row sums for this wave half
        atomicAdd(&sstat[cl], cs);
        atomicAdd(&sstat[128 + cl], cq);
      }
    }
  }
  if constexpr (STATS) {
    __syncthreads();
    if (tid < 128) {
      size_t pb = ((size_t)blockIdx.y * gridDim.x + blockIdx.x) * 256;
      partial[pb + tid]       = sstat[tid];
      partial[pb + 128 + tid] = sstat[128 + tid];
    }
  }
}

// ---------------- BatchNorm finalize / stats / apply ----------------

// partials from gemm_bf16<STATS>: [by*GX+bx][{sum,sumsq}][128]
__global__ __launch_bounds__(64) void finalize_gemm(const float* __restrict__ partial, int GX, int n,
                                                    const float* __restrict__ g,
                                                    const float* __restrict__ be,
                                                    float* __restrict__ scale,
                                                    float* __restrict__ shift) {
  int c = blockIdx.x;
  int by = c >> 7, cl = c & 127;
  float s = 0.f, q = 0.f;
  for (int bx = threadIdx.x; bx < GX; bx += 64) {
    const float* pb = partial + ((size_t)by * GX + bx) * 256;
    s += pb[cl]; q += pb[128 + cl];
  }
  #pragma unroll
  for (int d = 32; d > 0; d >>= 1) { s += __shfl_down(s, d, 64); q += __shfl_down(q, d, 64); }
  if (threadIdx.x == 0) {
    float inv_n = 1.0f / (float)n;
    float mu = s * inv_n;
    float var = q * inv_n - mu * mu;
    float rs = rsqrtf(var + BN_EPS);
    float sc = rs * g[c];
    scale[c] = sc;
    shift[c] = fmaf(-mu, sc, be[c]);
  }
}

template<int F>
__global__ __launch_bounds__(256) void stats_bf16(const u16* __restrict__ m, int n,
                                                  float* __restrict__ partial) {
  constexpr int COLS = F / 4;
  constexpr int RG = 256 / COLS;
  int c4 = threadIdx.x % COLS;
  int rg = threadIdx.x / COLS;
  float s[4] = {}, q[4] = {};
  for (int r = blockIdx.x * RG + rg; r < n; r += gridDim.x * RG) {
    u16 t[4];
    *(uint2*)t = *(const uint2*)(m + (size_t)r * F + c4 * 4);
    #pragma unroll
    for (int j = 0; j < 4; ++j) { float v = bf2f(t[j]); s[j] += v; q[j] = fmaf(v, v, q[j]); }
  }
  __shared__ float ls[256][8];
  #pragma unroll
  for (int j = 0; j < 4; ++j) { ls[threadIdx.x][j] = s[j]; ls[threadIdx.x][4 + j] = q[j]; }
  __syncthreads();
  if (rg == 0) {
    for (int g = 1; g < RG; ++g) {
      #pragma unroll
      for (int j = 0; j < 4; ++j) {
        s[j] += ls[g * COLS + c4][j];
        q[j] += ls[g * COLS + c4][4 + j];
      }
    }
    #pragma unroll
    for (int j = 0; j < 4; ++j) {
      partial[(size_t)blockIdx.x * 2 * F + c4 * 4 + j]     = s[j];
      partial[(size_t)blockIdx.x * 2 * F + F + c4 * 4 + j] = q[j];
    }
  }
}

template<int F>
__global__ __launch_bounds__(64) void finalize_agg(const float* __restrict__ partial, int nb, int n,
                                                   const float* __restrict__ g,
                                                   const float* __restrict__ be,
                                                   float* __restrict__ scale,
                                                   float* __restrict__ shift) {
  int c = blockIdx.x;
  float s = 0.f, q = 0.f;
  for (int b = threadIdx.x; b < nb; b += 64) {
    s += partial[(size_t)b * 2 * F + c];
    q += partial[(size_t)b * 2 * F + F + c];
  }
  #pragma unroll
  for (int d = 32; d > 0; d >>= 1) { s += __shfl_down(s, d, 64); q += __shfl_down(q, d, 64); }
  if (threadIdx.x == 0) {
    float inv_n = 1.0f / (float)n;
    float mu = s * inv_n;
    float var = q * inv_n - mu * mu;
    float rs = rsqrtf(var + BN_EPS);
    float sc = rs * g[c];
    scale[c] = sc;
    shift[c] = fmaf(-mu, sc, be[c]);
  }
}

template<int F, bool RES>
__global__ __launch_bounds__(256) void apply_bf16(const u16* __restrict__ m,
                                                  const float* __restrict__ scale,
                                                  const float* __restrict__ shift,
                                                  const u16* __restrict__ res,
                                                  u16* __restrict__ out, int n) {
  int i = blockIdx.x * 256 + threadIdx.x;  // group of 8 feats
  if (i >= n * (F / 8)) return;
  int c = i & (F / 8 - 1);
  u16 t[8];
  *(uint4*)t = *(const uint4*)(m + (size_t)i * 8);
  float sc[8], sh[8];
  *(float4*)sc       = ((const float4*)scale)[c * 2];
  *(float4*)(sc + 4) = ((const float4*)scale)[c * 2 + 1];
  *(float4*)sh       = ((const float4*)shift)[c * 2];
  *(float4*)(sh + 4) = ((const float4*)shift)[c * 2 + 1];
  float h[8];
  #pragma unroll
  for (int j = 0; j < 8; ++j) h[j] = fmaxf(fmaf(bf2f(t[j]), sc[j], sh[j]), 0.f);
  if constexpr (RES) {
    u16 r[8];
    *(uint4*)r = *(const uint4*)(res + (size_t)i * 8);
    #pragma unroll
    for (int j = 0; j < 8; ++j) h[j] += bf2f(r[j]);
  }
  u16 o[8];
  #pragma unroll
  for (int j = 0; j < 8; ++j) o[j] = f2bf(h[j]);
  *(uint4*)(out + (size_t)i * 8) = *(uint4*)o;
}

// ---------------- launcher ----------------

extern "C" void kernel_launch(void* const* d_in, const int* in_sizes, int n_in,
                              void* d_out, int out_size, void* d_ws, size_t ws_size,
                              hipStream_t stream) {
  const float* x   = (const float*)d_in[0];
  const int*   ei  = (const int*)d_in[1];   // int32 per harness dtype rule
  const float* W0  = (const float*)d_in[2];
  const float* b0  = (const float*)d_in[3];
  const float* g0  = (const float*)d_in[4];
  const float* be0 = (const float*)d_in[5];
  const float* W1  = (const float*)d_in[6];
  const float* b1  = (const float*)d_in[7];
  const float* g1  = (const float*)d_in[8];
  const float* be1 = (const float*)d_in[9];
  const float* W2  = (const float*)d_in[10];
  const float* b2  = (const float*)d_in[11];
  float* out = (float*)d_out;

  const int N = in_sizes[0] / D_IN;
  const int E = in_sizes[1] / 2;
  const int* esrc = ei;
  const int* edst = ei + E;

  char* p = (char*)d_ws;
  auto alloc = [&](size_t bytes) { char* r = p; p += (bytes + 255) & ~(size_t)255; return r; };
  int* cnt     = (int*)alloc((size_t)2 * N * 4);   // cnt + cursor contiguous
  int* cursor  = cnt + N;
  int* rowptr  = (int*)alloc(((size_t)N + 1) * 4);
  int* col     = (int*)alloc((size_t)E * 4);
  float* dinv  = (float*)alloc((size_t)N * 4);
  const int nb = (N + 1023) / 1024;
  int* bsum    = (int*)alloc((size_t)nb * 4);
  int* boff    = (int*)alloc((size_t)nb * 4);
  const int MB = (N + 127) / 128;                  // gemm grid.x
  constexpr int SB = 128;
  float* partial = (float*)alloc((size_t)MB * 2 * 256 * 4);  // covers both layouts
  float* scalev  = (float*)alloc(256 * 4);
  float* shiftv  = (float*)alloc(256 * 4);
  u16* Wt0 = (u16*)alloc((size_t)256 * 128 * 2);
  u16* Wt1 = (u16*)alloc((size_t)256 * 256 * 2);
  u16* Wt2 = (u16*)alloc((size_t)128 * 256 * 2);
  // activation slots (aliased by disjoint live ranges):
  u16* slotX  = (u16*)alloc((size_t)N * 128 * 2);  // x_bf (L0), then m2 (L2)
  u16* slotAM = (u16*)alloc((size_t)N * 256 * 2);  // a0 (L0), then m1 (L1)
  u16* slotMH = (u16*)alloc((size_t)N * 256 * 2);  // m0 -> h0 in-place
  u16* slotAH = (u16*)alloc((size_t)N * 256 * 2);  // a1 -> h1 in-place
  u16* x_bf = slotX;  u16* m2 = slotX;
  u16* a0   = slotAM; u16* m1 = slotAM;
  u16* m0   = slotMH; u16* h0 = slotMH;
  u16* a1   = slotAH; u16* h1 = slotAH;
  (void)ws_size; (void)n_in; (void)out_size;

  // conversions + zero + graph preprocessing
  const int BX = (N * 32 + 255) / 256;
  zero_kernel<<<(2 * N + 255) / 256, 256, 0, stream>>>(cnt, 2 * N);
  prep_kernel<<<BX + 512, 256, 0, stream>>>(x, x_bf, W0, Wt0, W1, Wt1, W2, Wt2, N, BX);
  count_kernel<<<(E + 255) / 256, 256, 0, stream>>>(edst, E, cnt);
  scan_sum_kernel<<<nb, 1024, 0, stream>>>(cnt, N, bsum, dinv);
  scan_off_kernel<<<1, 64, 0, stream>>>(bsum, nb, boff, rowptr + N);
  scan_final_kernel<<<nb, 1024, 0, stream>>>(cnt, N, boff, rowptr);
  fill_kernel<<<(E + 255) / 256, 256, 0, stream>>>(esrc, edst, E, rowptr, cursor, col);

  const int aggGrid = (N + 3) / 4;

  // layer 0: a0 = Agg(x); m0 = a0@W0 + b0 (stats fused); h0 = relu(bn(m0))
  agg_bf16<128, false, false><<<aggGrid, 256, 0, stream>>>(x_bf, rowptr, col, dinv,
                                                           nullptr, nullptr, a0, N);
  gemm_bf16<128, 256, true, true><<<dim3(MB, 2), 256, 0, stream>>>(a0, Wt0, b0, m0, partial, N);
  finalize_gemm<<<256, 64, 0, stream>>>(partial, MB, N, g0, be0, scalev, shiftv);
  apply_bf16<256, false><<<(N * 32 + 255) / 256, 256, 0, stream>>>(m0, scalev, shiftv,
                                                                   nullptr, h0, N);

  // layer 1: m1 = h0@W1; a1 = Agg(m1)+b1; h1 = relu(bn(a1)) + h0
  gemm_bf16<256, 256, false, false><<<dim3(MB, 2), 256, 0, stream>>>(h0, Wt1, nullptr, m1,
                                                                     nullptr, N);
  agg_bf16<256, true, false><<<aggGrid, 256, 0, stream>>>(m1, rowptr, col, dinv,
                                                          b1, nullptr, a1, N);
  stats_bf16<256><<<SB, 256, 0, stream>>>(a1, N, partial);
  finalize_agg<256><<<256, 64, 0, stream>>>(partial, SB, N, g1, be1, scalev, shiftv);
  apply_bf16<256, true><<<(N * 32 + 255) / 256, 256, 0, stream>>>(a1, scalev, shiftv,
                                                                  h0, h1, N);

  // layer 2: m2 = h1@W2; out = Agg(m2) + b2 + x (x fp32 exact)
  gemm_bf16<256, 128, false, false><<<dim3(MB, 1), 256, 0, stream>>>(h1, Wt2, nullptr, m2,
                                                                     nullptr, N);
  agg_bf16<128, true, true><<<aggGrid, 256, 0, stream>>>(m2, rowptr, col, dinv,
                                                         b2, x, out, N);
}

// Round 6
// 409.323 us; speedup vs baseline: 1.9121x; 1.0736x over previous
//
#include <hip/hip_runtime.h>

#define BN_EPS 1e-5f

static constexpr int D_IN = 128;

using u16 = unsigned short;
using f32x4  = __attribute__((ext_vector_type(4))) float;
using bf16x8 = __attribute__((ext_vector_type(8))) __bf16;

union FragU { uint4 u; bf16x8 v; };

__device__ __forceinline__ u16 f2bf(float f) {
  unsigned int u = __float_as_uint(f);
  u += 0x7FFFu + ((u >> 16) & 1u);   // RNE
  return (u16)(u >> 16);
}
__device__ __forceinline__ float bf2f(u16 h) {
  return __uint_as_float(((unsigned int)h) << 16);
}

// ---------------- graph preprocessing (int32 edge_index per harness rule) -----

__global__ __launch_bounds__(256) void count_kernel(const int* __restrict__ dst, int E,
                                                    int* __restrict__ cnt) {
  int e = blockIdx.x * 256 + threadIdx.x;
  if (e < E) atomicAdd(&cnt[dst[e]], 1);
}

// block sums for scan + dinv = rsqrt(deg+1) fused
__global__ __launch_bounds__(1024) void scan_sum_kernel(const int* __restrict__ cnt, int n,
                                                        int* __restrict__ bsum,
                                                        float* __restrict__ dinv) {
  __shared__ int sdata[1024];
  int i = blockIdx.x * 1024 + threadIdx.x;
  int v = (i < n) ? cnt[i] : 0;
  if (i < n) dinv[i] = rsqrtf((float)v + 1.0f);  // +1: self loop
  sdata[threadIdx.x] = v;
  __syncthreads();
  for (int s = 512; s > 0; s >>= 1) {
    if (threadIdx.x < s) sdata[threadIdx.x] += sdata[threadIdx.x + s];
    __syncthreads();
  }
  if (threadIdx.x == 0) bsum[blockIdx.x] = sdata[0];
}

__global__ void scan_off_kernel(const int* __restrict__ bsum, int nb,
                                int* __restrict__ boff, int* __restrict__ rowptr_last) {
  if (threadIdx.x == 0 && blockIdx.x == 0) {
    int run = 0;
    for (int b = 0; b < nb; ++b) { boff[b] = run; run += bsum[b]; }
    *rowptr_last = run;
  }
}

__global__ __launch_bounds__(1024) void scan_final_kernel(const int* __restrict__ cnt, int n,
                                                          const int* __restrict__ boff,
                                                          int* __restrict__ rowptr) {
  __shared__ int wt[16];
  int i = blockIdx.x * 1024 + threadIdx.x;
  int lane = threadIdx.x & 63, w = threadIdx.x >> 6;
  int v = (i < n) ? cnt[i] : 0;
  int x = v;
  #pragma unroll
  for (int d = 1; d < 64; d <<= 1) {
    int t = __shfl_up(x, d, 64);
    if (lane >= d) x += t;
  }
  if (lane == 63) wt[w] = x;
  __syncthreads();
  if (threadIdx.x == 0) {
    int run = 0;
    #pragma unroll
    for (int k = 0; k < 16; ++k) { int t = wt[k]; wt[k] = run; run += t; }
  }
  __syncthreads();
  if (i < n) rowptr[i] = x - v + wt[w] + boff[blockIdx.x];
}

__global__ __launch_bounds__(256) void fill_kernel(const int* __restrict__ src,
                                                   const int* __restrict__ dst, int E,
                                                   const int* __restrict__ rowptr,
                                                   int* __restrict__ cursor, int* __restrict__ col) {
  int e = blockIdx.x * 256 + threadIdx.x;
  if (e < E) {
    int d = dst[e];
    int p = atomicAdd(&cursor[d], 1);
    col[rowptr[d] + p] = src[e];
  }
}

// -------- fused prep: zero cnt/cursor, x->bf16, W0/W1/W2 -> transposed bf16 ---

__global__ __launch_bounds__(256) void prep_kernel(int* __restrict__ zbuf, int nz, int BZ,
                                                   const float* __restrict__ x, u16* __restrict__ x_bf,
                                                   const float* __restrict__ W0, u16* __restrict__ Wt0,
                                                   const float* __restrict__ W1, u16* __restrict__ Wt1,
                                                   const float* __restrict__ W2, u16* __restrict__ Wt2,
                                                   int N, int BX) {
  int b = blockIdx.x, tid = threadIdx.x;
  if (b < BZ) {
    int i = b * 256 + tid;
    if (i < nz) zbuf[i] = 0;
  } else if (b < BZ + BX) {
    int i = (b - BZ) * 256 + tid;
    if (i < N * 32) {
      float4 v = ((const float4*)x)[i];
      u16 o[4] = { f2bf(v.x), f2bf(v.y), f2bf(v.z), f2bf(v.w) };
      ((uint2*)x_bf)[i] = *(uint2*)o;
    }
  } else if (b < BZ + BX + 128) {       // W0 [128][256] -> Wt0 [256][128]
    int idx = (b - BZ - BX) * 256 + tid;
    int k = idx >> 8, nc = idx & 255;
    Wt0[nc * 128 + k] = f2bf(W0[idx]);
  } else if (b < BZ + BX + 384) {       // W1 [256][256] -> Wt1 [256][256]
    int idx = (b - BZ - BX - 128) * 256 + tid;
    int k = idx >> 8, nc = idx & 255;
    Wt1[nc * 256 + k] = f2bf(W1[idx]);
  } else {                              // W2 [256][128] -> Wt2 [128][256]
    int idx = (b - BZ - BX - 384) * 256 + tid;
    int k = idx >> 7, nc = idx & 127;
    Wt2[nc * 256 + k] = f2bf(W2[idx]);
  }
}

// ---------------- aggregation over bf16 features ----------------
// out[i] = dinv[i]*(sum_j dinv[j]*in[j] + dinv[i]*in[i]) (+bias)(+x fp32 if FINAL)

template<int F, bool BIAS, bool FINAL>
__global__ __launch_bounds__(256) void agg_bf16(const u16* __restrict__ in,
                                                const int* __restrict__ rowptr,
                                                const int* __restrict__ col,
                                                const float* __restrict__ dinv,
                                                const float* __restrict__ bias,
                                                const float* __restrict__ xres,
                                                void* __restrict__ outv, int n) {
  constexpr int V = F / 64;  // bf16 elems per lane (2 or 4)
  int node = blockIdx.x * 4 + (threadIdx.x >> 6);
  if (node >= n) return;
  int lane = threadIdx.x & 63;
  const int off = lane * V;
  const size_t rowbase = (size_t)node * F + off;

  float di = dinv[node];
  float acc[V];
  {
    u16 t[V];
    if constexpr (V == 4) *(uint2*)t = *(const uint2*)(in + rowbase);
    else                  *(unsigned int*)t = *(const unsigned int*)(in + rowbase);
    #pragma unroll
    for (int j = 0; j < V; ++j) acc[j] = di * bf2f(t[j]);
  }

  int e   = __builtin_amdgcn_readfirstlane(rowptr[node]);
  int end = __builtin_amdgcn_readfirstlane(rowptr[node + 1]);
  for (; e + 4 <= end; e += 4) {
    int s0 = col[e], s1 = col[e + 1], s2 = col[e + 2], s3 = col[e + 3];
    float w0 = dinv[s0], w1 = dinv[s1], w2 = dinv[s2], w3 = dinv[s3];
    u16 t0[V], t1[V], t2[V], t3[V];
    if constexpr (V == 4) {
      *(uint2*)t0 = *(const uint2*)(in + (size_t)s0 * F + off);
      *(uint2*)t1 = *(const uint2*)(in + (size_t)s1 * F + off);
      *(uint2*)t2 = *(const uint2*)(in + (size_t)s2 * F + off);
      *(uint2*)t3 = *(const uint2*)(in + (size_t)s3 * F + off);
    } else {
      *(unsigned int*)t0 = *(const unsigned int*)(in + (size_t)s0 * F + off);
      *(unsigned int*)t1 = *(const unsigned int*)(in + (size_t)s1 * F + off);
      *(unsigned int*)t2 = *(const unsigned int*)(in + (size_t)s2 * F + off);
      *(unsigned int*)t3 = *(const unsigned int*)(in + (size_t)s3 * F + off);
    }
    #pragma unroll
    for (int j = 0; j < V; ++j) acc[j] = fmaf(w0, bf2f(t0[j]), acc[j]);
    #pragma unroll
    for (int j = 0; j < V; ++j) acc[j] = fmaf(w1, bf2f(t1[j]), acc[j]);
    #pragma unroll
    for (int j = 0; j < V; ++j) acc[j] = fmaf(w2, bf2f(t2[j]), acc[j]);
    #pragma unroll
    for (int j = 0; j < V; ++j) acc[j] = fmaf(w3, bf2f(t3[j]), acc[j]);
  }
  for (; e < end; ++e) {
    int s0 = col[e];
    float w0 = dinv[s0];
    u16 t0[V];
    if constexpr (V == 4) *(uint2*)t0 = *(const uint2*)(in + (size_t)s0 * F + off);
    else                  *(unsigned int*)t0 = *(const unsigned int*)(in + (size_t)s0 * F + off);
    #pragma unroll
    for (int j = 0; j < V; ++j) acc[j] = fmaf(w0, bf2f(t0[j]), acc[j]);
  }

  #pragma unroll
  for (int j = 0; j < V; ++j) acc[j] *= di;
  if constexpr (BIAS) {
    #pragma unroll
    for (int j = 0; j < V; ++j) acc[j] += bias[off + j];
  }
  if constexpr (FINAL) {
    float* out = (float*)outv;
    float xr[V];
    if constexpr (V == 2) *(float2*)xr = *(const float2*)(xres + rowbase);
    else                  *(float4*)xr = *(const float4*)(xres + rowbase);
    #pragma unroll
    for (int j = 0; j < V; ++j) acc[j] += xr[j];
    if constexpr (V == 2) *(float2*)(out + rowbase) = *(float2*)acc;
    else                  *(float4*)(out + rowbase) = *(float4*)acc;
  } else {
    u16* out = (u16*)outv;
    u16 o[V];
    #pragma unroll
    for (int j = 0; j < V; ++j) o[j] = f2bf(acc[j]);
    if constexpr (V == 4) *(uint2*)(out + rowbase) = *(uint2*)o;
    else                  *(unsigned int*)(out + rowbase) = *(unsigned int*)o;
  }
}

// agg (F=256) with fused BN partial stats: 4 waves x 8 nodes per block.
__global__ __launch_bounds__(256) void agg_stats_bf16(const u16* __restrict__ in,
                                                      const int* __restrict__ rowptr,
                                                      const int* __restrict__ col,
                                                      const float* __restrict__ dinv,
                                                      const float* __restrict__ bias,
                                                      u16* __restrict__ out,
                                                      float* __restrict__ partial, int n) {
  constexpr int F = 256, V = 4;
  __shared__ float sstat[512];
  const int tid = threadIdx.x;
  const int lane = tid & 63, wid = tid >> 6;
  const int off = lane * V;
  sstat[tid] = 0.f; sstat[tid + 256] = 0.f;
  __syncthreads();

  float s[V] = {}, q[V] = {};
  int base = blockIdx.x * 32 + wid * 8;
  for (int i = 0; i < 8; ++i) {
    int node = base + i;
    if (node >= n) break;
    const size_t rowbase = (size_t)node * F + off;
    float di = dinv[node];
    float acc[V];
    {
      u16 t[V];
      *(uint2*)t = *(const uint2*)(in + rowbase);
      #pragma unroll
      for (int j = 0; j < V; ++j) acc[j] = di * bf2f(t[j]);
    }
    int e   = __builtin_amdgcn_readfirstlane(rowptr[node]);
    int end = __builtin_amdgcn_readfirstlane(rowptr[node + 1]);
    for (; e + 4 <= end; e += 4) {
      int s0 = col[e], s1 = col[e + 1], s2 = col[e + 2], s3 = col[e + 3];
      float w0 = dinv[s0], w1 = dinv[s1], w2 = dinv[s2], w3 = dinv[s3];
      u16 t0[V], t1[V], t2[V], t3[V];
      *(uint2*)t0 = *(const uint2*)(in + (size_t)s0 * F + off);
      *(uint2*)t1 = *(const uint2*)(in + (size_t)s1 * F + off);
      *(uint2*)t2 = *(const uint2*)(in + (size_t)s2 * F + off);
      *(uint2*)t3 = *(const uint2*)(in + (size_t)s3 * F + off);
      #pragma unroll
      for (int j = 0; j < V; ++j) acc[j] = fmaf(w0, bf2f(t0[j]), acc[j]);
      #pragma unroll
      for (int j = 0; j < V; ++j) acc[j] = fmaf(w1, bf2f(t1[j]), acc[j]);
      #pragma unroll
      for (int j = 0; j < V; ++j) acc[j] = fmaf(w2, bf2f(t2[j]), acc[j]);
      #pragma unroll
      for (int j = 0; j < V; ++j) acc[j] = fmaf(w3, bf2f(t3[j]), acc[j]);
    }
    for (; e < end; ++e) {
      int s0 = col[e];
      float w0 = dinv[s0];
      u16 t0[V];
      *(uint2*)t0 = *(const uint2*)(in + (size_t)s0 * F + off);
      #pragma unroll
      for (int j = 0; j < V; ++j) acc[j] = fmaf(w0, bf2f(t0[j]), acc[j]);
    }
    u16 o[V];
    #pragma unroll
    for (int j = 0; j < V; ++j) {
      acc[j] = fmaf(acc[j], di, bias[off + j]);
      s[j] += acc[j]; q[j] = fmaf(acc[j], acc[j], q[j]);
      o[j] = f2bf(acc[j]);
    }
    *(uint2*)(out + rowbase) = *(uint2*)o;
  }
  #pragma unroll
  for (int j = 0; j < V; ++j) atomicAdd(&sstat[off + j], s[j]);
  #pragma unroll
  for (int j = 0; j < V; ++j) atomicAdd(&sstat[256 + off + j], q[j]);
  __syncthreads();
  float* pb = partial + (size_t)blockIdx.x * 512;
  pb[tid] = sstat[tid];
  pb[tid + 256] = sstat[tid + 256];
}

// ------- streaming MFMA GEMM: C[M,NN] = A[M,K] @ Wt[NN,K]^T (+bias) ----------
// B (one 128-col block of Wt) lives entirely in LDS (<=64KB), loaded once via
// global_load_lds with pre-swizzled source chunks (involution c^(r&7) on 16B
// chunks, linear LDS dest). ONE barrier; then each wave independently streams
// 64-row A chunks: per ks-step 4 global A-frag loads + 8 swizzled ds_read_b128
// + 32 dep-free MFMAs. No barriers in the main loop. STATS: per-block BN
// partials (padded rows masked) via shfl + LDS atomics.

template<int K, int NN, bool BIAS, bool STATS>
__global__ __launch_bounds__(256, 2) void gemm_stream(const u16* __restrict__ A,
                                                      const u16* __restrict__ Wt,
                                                      const float* __restrict__ bias,
                                                      u16* __restrict__ C,
                                                      float* __restrict__ partial, int M) {
  constexpr int CPR = K / 8;           // 16B chunks per row of B
  __shared__ u16 Blds[128 * K];
  __shared__ float sstat[256];
  const int tid = threadIdx.x;
  const int lane = tid & 63;
  const int wid = tid >> 6;
  const int bn = blockIdx.y * 128;
  const int kh = lane >> 4;            // k-half-chunk 0..3

  if constexpr (STATS) { sstat[tid] = 0.f; }

  // stage B: 128 cols x K, swizzled source -> linear LDS
  const u16* Bsrc = Wt + (size_t)bn * K;
  #pragma unroll
  for (int i = 0; i < CPR / 2; ++i) {
    int flat = i * 256 + tid;
    int r = flat / CPR;
    int c = flat & (CPR - 1);
    __builtin_amdgcn_global_load_lds(
        (const __attribute__((address_space(1))) void*)(Bsrc + (size_t)r * K + (c ^ (r & 7)) * 8),
        (__attribute__((address_space(3))) void*)(&Blds[flat * 8]),
        16, 0, 0);
  }
  __syncthreads();

  float cs[8] = {}, cq[8] = {};
  const int nch = (M + 63) / 64;
  for (int ch = blockIdx.x * 4 + wid; ch < nch; ch += gridDim.x * 4) {
    const int r0 = ch * 64;
    // hoist A row pointers (clamped; garbage rows masked at store/stats)
    const u16* arow[4];
    #pragma unroll
    for (int rf = 0; rf < 4; ++rf) {
      int row = r0 + rf * 16 + (lane & 15);
      if (row >= M) row = M - 1;
      arow[rf] = A + (size_t)row * K + kh * 8;
    }
    f32x4 acc[4][8] = {};
    #pragma unroll
    for (int ks = 0; ks < K / 32; ++ks) {
      FragU a[4], b[8];
      #pragma unroll
      for (int rf = 0; rf < 4; ++rf)
        a[rf].u = *(const uint4*)(arow[rf] + ks * 32);
      #pragma unroll
      for (int cf = 0; cf < 8; ++cf) {
        int rr = cf * 16 + (lane & 15);
        int c = ks * 4 + kh;
        b[cf].u = *(const uint4*)(&Blds[rr * K + ((c ^ (rr & 7)) * 8)]);
      }
      #pragma unroll
      for (int rf = 0; rf < 4; ++rf)
        #pragma unroll
        for (int cf = 0; cf < 8; ++cf)
          acc[rf][cf] = __builtin_amdgcn_mfma_f32_16x16x32_bf16(a[rf].v, b[cf].v,
                                                                acc[rf][cf], 0, 0, 0);
    }
    // epilogue: C/D frag mapping col=lane&15, row=(lane>>4)*4+j
    #pragma unroll
    for (int cf = 0; cf < 8; ++cf) {
      int gc = bn + cf * 16 + (lane & 15);
      float bv = 0.f;
      if constexpr (BIAS) bv = bias[gc];
      #pragma unroll
      for (int rf = 0; rf < 4; ++rf) {
        int gr0 = r0 + rf * 16 + kh * 4;
        #pragma unroll
        for (int j = 0; j < 4; ++j) {
          int gr = gr0 + j;
          if (gr < M) {
            float v = acc[rf][cf][j] + bv;
            C[(size_t)gr * NN + gc] = f2bf(v);
            if constexpr (STATS) { cs[cf] += v; cq[cf] = fmaf(v, v, cq[cf]); }
          }
        }
      }
    }
  }

  if constexpr (STATS) {
    #pragma unroll
    for (int cf = 0; cf < 8; ++cf) {
      float s = cs[cf], q = cq[cf];
      s += __shfl_xor(s, 16, 64); q += __shfl_xor(q, 16, 64);
      s += __shfl_xor(s, 32, 64); q += __shfl_xor(q, 32, 64);
      if (kh == 0) {
        int cl = cf * 16 + (lane & 15);
        atomicAdd(&sstat[cl], s);
        atomicAdd(&sstat[128 + cl], q);
      }
    }
    __syncthreads();
    if (tid < 128) {
      size_t pb = ((size_t)blockIdx.y * gridDim.x + blockIdx.x) * 256;
      partial[pb + tid]       = sstat[tid];
      partial[pb + 128 + tid] = sstat[128 + tid];
    }
  }
}

// ---------------- BatchNorm finalize / apply ----------------

// partials from gemm_stream<STATS>: [by*GX+bx][{sum[128],sumsq[128]}]
__global__ __launch_bounds__(64) void finalize_gemm(const float* __restrict__ partial, int GX, int n,
                                                    const float* __restrict__ g,
                                                    const float* __restrict__ be,
                                                    float* __restrict__ scale,
                                                    float* __restrict__ shift) {
  int c = blockIdx.x;
  int by = c >> 7, cl = c & 127;
  float s = 0.f, q = 0.f;
  for (int bx = threadIdx.x; bx < GX; bx += 64) {
    const float* pb = partial + ((size_t)by * GX + bx) * 256;
    s += pb[cl]; q += pb[128 + cl];
  }
  #pragma unroll
  for (int d = 32; d > 0; d >>= 1) { s += __shfl_down(s, d, 64); q += __shfl_down(q, d, 64); }
  if (threadIdx.x == 0) {
    float inv_n = 1.0f / (float)n;
    float mu = s * inv_n;
    float var = q * inv_n - mu * mu;
    float rs = rsqrtf(var + BN_EPS);
    float sc = rs * g[c];
    scale[c] = sc;
    shift[c] = fmaf(-mu, sc, be[c]);
  }
}

// partials from agg_stats_bf16: [b][{sum[256],sumsq[256]}]
__global__ __launch_bounds__(64) void finalize_agg(const float* __restrict__ partial, int nb, int n,
                                                   const float* __restrict__ g,
                                                   const float* __restrict__ be,
                                                   float* __restrict__ scale,
                                                   float* __restrict__ shift) {
  int c = blockIdx.x;
  float s = 0.f, q = 0.f;
  for (int b = threadIdx.x; b < nb; b += 64) {
    s += partial[(size_t)b * 512 + c];
    q += partial[(size_t)b * 512 + 256 + c];
  }
  #pragma unroll
  for (int d = 32; d > 0; d >>= 1) { s += __shfl_down(s, d, 64); q += __shfl_down(q, d, 64); }
  if (threadIdx.x == 0) {
    float inv_n = 1.0f / (float)n;
    float mu = s * inv_n;
    float var = q * inv_n - mu * mu;
    float rs = rsqrtf(var + BN_EPS);
    float sc = rs * g[c];
    scale[c] = sc;
    shift[c] = fmaf(-mu, sc, be[c]);
  }
}

template<int F, bool RES>
__global__ __launch_bounds__(256) void apply_bf16(const u16* __restrict__ m,
                                                  const float* __restrict__ scale,
                                                  const float* __restrict__ shift,
                                                  const u16* __restrict__ res,
                                                  u16* __restrict__ out, int n) {
  int i = blockIdx.x * 256 + threadIdx.x;  // group of 8 feats
  if (i >= n * (F / 8)) return;
  int c = i & (F / 8 - 1);
  u16 t[8];
  *(uint4*)t = *(const uint4*)(m + (size_t)i * 8);
  float sc[8], sh[8];
  *(float4*)sc       = ((const float4*)scale)[c * 2];
  *(float4*)(sc + 4) = ((const float4*)scale)[c * 2 + 1];
  *(float4*)sh       = ((const float4*)shift)[c * 2];
  *(float4*)(sh + 4) = ((const float4*)shift)[c * 2 + 1];
  float h[8];
  #pragma unroll
  for (int j = 0; j < 8; ++j) h[j] = fmaxf(fmaf(bf2f(t[j]), sc[j], sh[j]), 0.f);
  if constexpr (RES) {
    u16 r[8];
    *(uint4*)r = *(const uint4*)(res + (size_t)i * 8);
    #pragma unroll
    for (int j = 0; j < 8; ++j) h[j] += bf2f(r[j]);
  }
  u16 o[8];
  #pragma unroll
  for (int j = 0; j < 8; ++j) o[j] = f2bf(h[j]);
  *(uint4*)(out + (size_t)i * 8) = *(uint4*)o;
}

// ---------------- launcher ----------------

extern "C" void kernel_launch(void* const* d_in, const int* in_sizes, int n_in,
                              void* d_out, int out_size, void* d_ws, size_t ws_size,
                              hipStream_t stream) {
  const float* x   = (const float*)d_in[0];
  const int*   ei  = (const int*)d_in[1];   // int32 per harness dtype rule
  const float* W0  = (const float*)d_in[2];
  const float* b0  = (const float*)d_in[3];
  const float* g0  = (const float*)d_in[4];
  const float* be0 = (const float*)d_in[5];
  const float* W1  = (const float*)d_in[6];
  const float* b1  = (const float*)d_in[7];
  const float* g1  = (const float*)d_in[8];
  const float* be1 = (const float*)d_in[9];
  const float* W2  = (const float*)d_in[10];
  const float* b2  = (const float*)d_in[11];
  float* out = (float*)d_out;

  const int N = in_sizes[0] / D_IN;
  const int E = in_sizes[1] / 2;
  const int* esrc = ei;
  const int* edst = ei + E;

  char* p = (char*)d_ws;
  auto alloc = [&](size_t bytes) { char* r = p; p += (bytes + 255) & ~(size_t)255; return r; };
  int* cnt     = (int*)alloc((size_t)2 * N * 4);   // cnt + cursor contiguous
  int* cursor  = cnt + N;
  int* rowptr  = (int*)alloc(((size_t)N + 1) * 4);
  int* col     = (int*)alloc((size_t)E * 4);
  float* dinv  = (float*)alloc((size_t)N * 4);
  const int nb = (N + 1023) / 1024;
  int* bsum    = (int*)alloc((size_t)nb * 4);
  int* boff    = (int*)alloc((size_t)nb * 4);
  const int AB = (N + 31) / 32;                    // agg_stats blocks
  float* partial = (float*)alloc((size_t)AB * 512 * 4);  // covers gemm layout too
  float* scalev  = (float*)alloc(256 * 4);
  float* shiftv  = (float*)alloc(256 * 4);
  u16* Wt0 = (u16*)alloc((size_t)256 * 128 * 2);
  u16* Wt1 = (u16*)alloc((size_t)256 * 256 * 2);
  u16* Wt2 = (u16*)alloc((size_t)128 * 256 * 2);
  // activation slots (aliased by disjoint live ranges):
  u16* slotX  = (u16*)alloc((size_t)N * 128 * 2);  // x_bf (L0), then m2 (L2)
  u16* slotAM = (u16*)alloc((size_t)N * 256 * 2);  // a0 (L0), then m1 (L1)
  u16* slotMH = (u16*)alloc((size_t)N * 256 * 2);  // m0 -> h0 in-place
  u16* slotAH = (u16*)alloc((size_t)N * 256 * 2);  // a1 -> h1 in-place
  u16* x_bf = slotX;  u16* m2 = slotX;
  u16* a0   = slotAM; u16* m1 = slotAM;
  u16* m0   = slotMH; u16* h0 = slotMH;
  u16* a1   = slotAH; u16* h1 = slotAH;
  (void)ws_size; (void)n_in; (void)out_size;

  // fused prep (zero + conversions) + graph preprocessing
  const int BZ = (2 * N + 255) / 256;
  const int BX = (N * 32 + 255) / 256;
  prep_kernel<<<BZ + BX + 512, 256, 0, stream>>>(cnt, 2 * N, BZ, x, x_bf,
                                                 W0, Wt0, W1, Wt1, W2, Wt2, N, BX);
  count_kernel<<<(E + 255) / 256, 256, 0, stream>>>(edst, E, cnt);
  scan_sum_kernel<<<nb, 1024, 0, stream>>>(cnt, N, bsum, dinv);
  scan_off_kernel<<<1, 64, 0, stream>>>(bsum, nb, boff, rowptr + N);
  scan_final_kernel<<<nb, 1024, 0, stream>>>(cnt, N, boff, rowptr);
  fill_kernel<<<(E + 255) / 256, 256, 0, stream>>>(esrc, edst, E, rowptr, cursor, col);

  const int aggGrid = (N + 3) / 4;
  const int GX = 196;   // waves per col-block = 784 ~= 782 row chunks

  // layer 0: a0 = Agg(x); m0 = a0@W0 + b0 (stats fused); h0 = relu(bn(m0))
  agg_bf16<128, false, false><<<aggGrid, 256, 0, stream>>>(x_bf, rowptr, col, dinv,
                                                           nullptr, nullptr, a0, N);
  gemm_stream<128, 256, true, true><<<dim3(GX, 2), 256, 0, stream>>>(a0, Wt0, b0, m0, partial, N);
  finalize_gemm<<<256, 64, 0, stream>>>(partial, GX, N, g0, be0, scalev, shiftv);
  apply_bf16<256, false><<<(N * 32 + 255) / 256, 256, 0, stream>>>(m0, scalev, shiftv,
                                                                   nullptr, h0, N);

  // layer 1: m1 = h0@W1; a1 = Agg(m1)+b1 (stats fused); h1 = relu(bn(a1)) + h0
  gemm_stream<256, 256, false, false><<<dim3(GX, 2), 256, 0, stream>>>(h0, Wt1, nullptr, m1,
                                                                       nullptr, N);
  agg_stats_bf16<<<AB, 256, 0, stream>>>(m1, rowptr, col, dinv, b1, a1, partial, N);
  finalize_agg<<<256, 64, 0, stream>>>(partial, AB, N, g1, be1, scalev, shiftv);
  apply_bf16<256, true><<<(N * 32 + 255) / 256, 256, 0, stream>>>(a1, scalev, shiftv,
                                                                  h0, h1, N);

  // layer 2: m2 = h1@W2; out = Agg(m2) + b2 + x (x fp32 exact)
  gemm_stream<256, 128, false, false><<<dim3(GX, 1), 256, 0, stream>>>(h1, Wt2, nullptr, m2,
                                                                       nullptr, N);
  agg_bf16<128, true, true><<<aggGrid, 256, 0, stream>>>(m2, rowptr, col, dinv,
                                                         b2, x, out, N);
}